// Round 5
// baseline (437.499 us; speedup 1.0000x reference)
//
#include <hip/hip_runtime.h>

// Gather + ragged segment XOR reduction.
// History: R1/R2 direct gather = 142 us, bound by L2-miss line fills (20-32 MB
// table vs 4 MB/XCD L2). R4: bucket-by-slice + XCD-pinned gather -> gather got
// fast (<67 us) but bucket_kernel cost 67 us (79 KB LDS -> 17% occupancy,
// serial pass-2). R5: single-pass bucketizer (tiny LDS, global rank atomics,
// fixed-cap buckets) + gather with 3 aligned loads (2x dwordx2 + dword) and
// packed 64-bit LDS atomicXor.

#define HPG  256     // hints per group
#define NSL  16      // slices (idx>>16), N <= 2^20
#define CAP  1344    // bucket capacity per (group,slice); mean ~1024, +9 sigma

__device__ __forceinline__ int clip_idx(int v, int N) {
    return min(max(v, 0), N - 1);
}

__device__ __forceinline__ unsigned long long pk64(int lo, int hi) {
    return (unsigned long long)(unsigned int)lo |
           ((unsigned long long)(unsigned int)hi << 32);
}

// Parity-aligned 20-byte row load: 3 transactions, no padded table.
// even idx: x2 @ d0, x2 @ d0+2, dword @ d0+4
// odd  idx: dword @ d0, x2 @ d0+1, x2 @ d0+3
__device__ __forceinline__ void load_row5(const int* __restrict__ e, int idx,
                                          int& e0, int& e1, int& e2, int& e3, int& e4) {
    const int d0 = idx * 5;
    const bool even = (idx & 1) == 0;
    const int pairBase = even ? (d0 >> 1) : ((d0 + 1) >> 1);
    int2 u = ((const int2*)e)[pairBase];
    int2 v = ((const int2*)e)[pairBase + 1];
    int  w = e[even ? d0 + 4 : d0];
    e0 = even ? u.x : w;
    e1 = even ? u.y : u.x;
    e2 = even ? v.x : u.y;
    e3 = even ? v.y : v.x;
    e4 = even ? w   : v.y;
}

// ---------------- Kernel A: single-pass bucketize ----------------
// Block = one group of 256 hints, 1024 threads, ~16 iterations.
__global__ __launch_bounds__(1024) void bucket_kernel(
    const int* __restrict__ blocks,
    const int* __restrict__ offsets,
    const int* __restrict__ starts,
    const int* __restrict__ bs_ptr,
    const int* __restrict__ entries,     // overflow path only
    int* __restrict__ out,               // overflow path only
    unsigned short* __restrict__ bIdxLo,
    unsigned char*  __restrict__ bHint,
    unsigned int*   __restrict__ tabCnt, // [NG*NSL], zeroed before launch
    int H, int N, int T)
{
    __shared__ int lstart[HPG + 1];

    const int g  = blockIdx.x;
    const int t  = threadIdx.x;
    const int h0 = g * HPG;
    const int h1 = min(H, h0 + HPG);
    const int nh = h1 - h0;
    const int bs = bs_ptr[0];

    if (t < nh) lstart[t] = starts[h0 + t];
    if (t == 0) lstart[nh] = (h1 < H) ? starts[h1] : T;
    __syncthreads();

    const int tokBase = lstart[0];
    const int count   = lstart[nh] - tokBase;

    for (int i = t; i < count; i += 1024) {
        const int gpos = tokBase + i;
        const int idx  = clip_idx(blocks[gpos] * bs + offsets[gpos], N);
        const unsigned int s = (unsigned int)idx >> 16;

        // largest h with lstart[h] <= gpos
        int lo = 0, hi = nh - 1;
        while (lo < hi) {
            int m = (lo + hi + 1) >> 1;
            if (lstart[m] <= gpos) lo = m; else hi = m - 1;
        }

        const unsigned int rank = atomicAdd(&tabCnt[g * NSL + s], 1u);
        if (rank < CAP) {
            const size_t p = ((size_t)(g * NSL + s)) * CAP + rank;
            bIdxLo[p] = (unsigned short)(idx & 0xFFFF);
            bHint[p]  = (unsigned char)lo;
        } else {
            // statistically never at these sizes; correctness fallback
            int e0, e1, e2, e3, e4;
            load_row5(entries, idx, e0, e1, e2, e3, e4);
            int* o5 = out + (long)(h0 + lo) * 5;
            atomicXor(&o5[0], e0); atomicXor(&o5[1], e1);
            atomicXor(&o5[2], e2); atomicXor(&o5[3], e3);
            atomicXor(&o5[4], e4);
        }
    }
}

// ---------------- Kernel B: XCD-pinned gather + LDS accumulate ----------------
// Grid = 2048 (resident capacity) so blockIdx&7 -> XCD round-robin holds.
// Block (x,g) touches only slices {x, x+8} -> 2.62 MB, L2-resident per XCD.
__global__ __launch_bounds__(256) void gather_kernel(
    const unsigned short* __restrict__ bIdxLo,
    const unsigned char*  __restrict__ bHint,
    const unsigned int*   __restrict__ tabCnt,
    const int* __restrict__ entries,
    int* __restrict__ out,
    int H, int NG, int nSl, int groupsPerBlock)
{
    __shared__ unsigned long long accLL[HPG * 2];
    __shared__ int acc4[HPG];

    const int B = blockIdx.x;
    const int x = B & 7;
    const int g0 = B >> 3;
    const int t = threadIdx.x;
    const int gStride = gridDim.x >> 3;

    for (int k = 0; k < groupsPerBlock; ++k) {
        const int g = g0 + k * gStride;
        if (g >= NG) break;

        for (int i = t; i < HPG * 2; i += 256) accLL[i] = 0ull;
        for (int i = t; i < HPG; i += 256) acc4[i] = 0;
        __syncthreads();

        for (int s = x; s < nSl; s += 8) {
            const unsigned int cn =
                min(tabCnt[g * NSL + s], (unsigned int)CAP);
            const size_t base = ((size_t)(g * NSL + s)) * CAP;
            const int hiBits = s << 16;
            for (unsigned int i = t; i < cn; i += 256) {
                const int idx = hiBits | (int)bIdxLo[base + i];
                const int h   = (int)bHint[base + i];
                int e0, e1, e2, e3, e4;
                load_row5(entries, idx, e0, e1, e2, e3, e4);
                atomicXor(&accLL[h * 2 + 0], pk64(e0, e1));
                atomicXor(&accLL[h * 2 + 1], pk64(e2, e3));
                atomicXor(&acc4[h], e4);
            }
        }
        __syncthreads();

        const long obase = (long)g * HPG * 5;
        const long omax  = (long)H * 5;
        for (int h = t; h < HPG; h += 256) {
            const long o = obase + (long)h * 5;
            if (o + 4 < omax || o < omax) {
                unsigned long long v01 = accLL[h * 2 + 0];
                unsigned long long v23 = accLL[h * 2 + 1];
                int a0 = (int)(unsigned int)v01, a1 = (int)(unsigned int)(v01 >> 32);
                int a2 = (int)(unsigned int)v23, a3 = (int)(unsigned int)(v23 >> 32);
                int a4 = acc4[h];
                if (o + 0 < omax && a0) atomicXor(&out[o + 0], a0);
                if (o + 1 < omax && a1) atomicXor(&out[o + 1], a1);
                if (o + 2 < omax && a2) atomicXor(&out[o + 2], a2);
                if (o + 3 < omax && a3) atomicXor(&out[o + 3], a3);
                if (o + 4 < omax && a4) atomicXor(&out[o + 4], a4);
            }
        }
        __syncthreads();
    }
}

// ---------------- Fallback (R1): direct gather, wave per hint ----------------
__global__ __launch_bounds__(256) void hint_xor_wave(
    const int* __restrict__ entries,
    const int* __restrict__ blocks,
    const int* __restrict__ offsets,
    const int* __restrict__ starts,
    const int* __restrict__ sizes,
    const int* __restrict__ bs_ptr,
    int* __restrict__ out,
    int H, int N)
{
    const int gtid = blockIdx.x * blockDim.x + threadIdx.x;
    const int hint = gtid >> 6;
    const int lane = gtid & 63;
    if (hint >= H) return;

    const int start = starts[hint];
    const int size  = sizes[hint];
    const int bs    = bs_ptr[0];

    int a0 = 0, a1 = 0, a2 = 0, a3 = 0, a4 = 0;
    for (int j = lane; j < size; j += 64) {
        int idx = clip_idx(blocks[start + j] * bs + offsets[start + j], N);
        const int* row = entries + (size_t)idx * 5;
        a0 ^= row[0]; a1 ^= row[1]; a2 ^= row[2]; a3 ^= row[3]; a4 ^= row[4];
    }
    #pragma unroll
    for (int m = 1; m < 64; m <<= 1) {
        a0 ^= __shfl_xor(a0, m);
        a1 ^= __shfl_xor(a1, m);
        a2 ^= __shfl_xor(a2, m);
        a3 ^= __shfl_xor(a3, m);
        a4 ^= __shfl_xor(a4, m);
    }
    if (lane == 0) {
        int* o = out + (size_t)hint * 5;
        o[0] = a0; o[1] = a1; o[2] = a2; o[3] = a3; o[4] = a4;
    }
}

extern "C" void kernel_launch(void* const* d_in, const int* in_sizes, int n_in,
                              void* d_out, int out_size, void* d_ws, size_t ws_size,
                              hipStream_t stream) {
    const int* entries = (const int*)d_in[0];
    const int* blocks  = (const int*)d_in[1];
    const int* offsets = (const int*)d_in[2];
    const int* starts  = (const int*)d_in[3];
    const int* sizes   = (const int*)d_in[4];
    const int* bs      = (const int*)d_in[5];
    int* out = (int*)d_out;

    const int H = in_sizes[3];
    const int T = in_sizes[1];
    const int N = in_sizes[0] / 5;

    const int NG  = (H + HPG - 1) / HPG;
    const int nSl = (N + 65535) >> 16;

    // ws layout: tabCnt | bIdxLo | bHint
    const size_t tabOff = 0;
    const size_t tabBytes = (size_t)NG * NSL * sizeof(unsigned int);
    const size_t loOff  = (tabOff + tabBytes + 63) & ~(size_t)63;
    const size_t loBytes = (size_t)NG * NSL * CAP * sizeof(unsigned short);
    const size_t hOff   = loOff + loBytes;
    const size_t need   = hOff + (size_t)NG * NSL * CAP + 64;

    const bool ok = (N <= (1 << 20)) && (nSl <= NSL) && (ws_size >= need);

    if (ok) {
        unsigned int*   tabCnt = (unsigned int*)((char*)d_ws + tabOff);
        unsigned short* bIdxLo = (unsigned short*)((char*)d_ws + loOff);
        unsigned char*  bHint  = (unsigned char*)((char*)d_ws + hOff);

        hipMemsetAsync(d_out, 0, (size_t)out_size * sizeof(int), stream);
        hipMemsetAsync(tabCnt, 0, tabBytes, stream);

        hipLaunchKernelGGL(bucket_kernel, dim3(NG), dim3(1024), 0, stream,
                           blocks, offsets, starts, bs, entries, out,
                           bIdxLo, bHint, tabCnt, H, N, T);

        int gridB = 2048;
        if (gridB > NG * 8) gridB = NG * 8;
        const int gStride = gridB >> 3;
        const int gpb = (NG + gStride - 1) / gStride;

        hipLaunchKernelGGL(gather_kernel, dim3(gridB), dim3(256), 0, stream,
                           bIdxLo, bHint, tabCnt, entries, out,
                           H, NG, nSl, gpb);
    } else {
        const long total_threads = (long)H * 64;
        const int block = 256;
        const int grid = (int)((total_threads + block - 1) / block);
        hipLaunchKernelGGL(hint_xor_wave, dim3(grid), dim3(block), 0, stream,
                           entries, blocks, offsets, starts, sizes, bs, out, H, N);
    }
}

// Round 6
// 189.146 us; speedup vs baseline: 2.3130x; 2.3130x over previous
//
#include <hip/hip_runtime.h>

// Gather + ragged segment XOR reduction.
// History:
//  R1/R2 direct gather: 142 us, L2-miss line-fill bound (20-32 MB table vs
//    4 MB/XCD L2), independent of request count.
//  R4: bucket-by-slice + XCD-pinned gather. Gather got fast (~60 us) but
//    bucket cost 67 us (79 KB LDS -> 17% occupancy + serial pass-2).
//  R5: global-atomic rank bucketizer: 250 us. WRITE 139 MB for 25 MB payload
//    (scattered 2B/1B stores) + 8.4M global atomics. Reverted.
//  R6: LDS-staged ordered scatter (R4's write-merging) + binary-search hint
//    labeling (kills pass-2) + HPG=128/1024-thread blocks (full occupancy).
//    Exact chunk allocation in the group's own CSR range (no cursor, no CAP).
//    Kernel B = proven R4 gather, but 1 u32 bucket read/token.

#define HPG        128     // hints per group
#define NSL        16      // slices (idx>>16), N <= 2^20
#define STAGE_CAP  12288   // tokens staged in LDS; mean 8192, +10 sigma

__device__ __forceinline__ int clip_idx(int v, int N) {
    return min(max(v, 0), N - 1);
}

// ---------------- Kernel A: bucketize (one group per block) ----------------
__global__ __launch_bounds__(1024) void bucket_kernel(
    const int* __restrict__ blocks,
    const int* __restrict__ offsets,
    const int* __restrict__ starts,
    const int* __restrict__ bs_ptr,
    const int* __restrict__ entries,     // overflow path only
    int* __restrict__ out,               // overflow path only
    unsigned int* __restrict__ buck,     // [T] u32: idx(20) | localHint(7..12)
    unsigned int* __restrict__ tab,      // [NG*NSL*2] {absBase, count}
    int H, int N, int T)
{
    __shared__ unsigned int stage[STAGE_CAP];
    __shared__ int lstart[HPG + 1];
    __shared__ unsigned int cnt[NSL], off[NSL], lcur[NSL];

    const int g  = blockIdx.x;
    const int t  = threadIdx.x;
    const int h0 = g * HPG;
    const int h1 = min(H, h0 + HPG);
    const int nh = h1 - h0;
    const int bs = bs_ptr[0];

    if (t < nh) lstart[t] = starts[h0 + t];
    if (t == 0) lstart[nh] = (h1 < H) ? starts[h1] : T;
    if (t < NSL) { cnt[t] = 0; lcur[t] = 0; }
    __syncthreads();

    const int tokBase = lstart[0];
    const int count   = lstart[nh] - tokBase;
    const int staged  = min(count, STAGE_CAP);

    // pass 1: idx + hint (binary search) -> LDS stage; per-slice histogram
    for (int i = t; i < staged; i += 1024) {
        const int gpos = tokBase + i;
        const int idx  = clip_idx(blocks[gpos] * bs + offsets[gpos], N);
        int lo = 0, hi = nh - 1;                 // largest h: lstart[h] <= gpos
        while (lo < hi) {
            int m = (lo + hi + 1) >> 1;
            if (lstart[m] <= gpos) lo = m; else hi = m - 1;
        }
        stage[i] = (unsigned int)idx | ((unsigned int)lo << 20);
        atomicAdd(&cnt[(unsigned int)idx >> 16], 1u);
    }
    __syncthreads();

    // exclusive prefix over 16 slice counts
    if (t == 0) {
        unsigned int run = 0;
        for (int s = 0; s < NSL; ++s) { off[s] = run; run += cnt[s]; }
    }
    __syncthreads();

    if (t < NSL) {
        tab[(g * NSL + t) * 2 + 0] = (unsigned int)tokBase + off[t];
        tab[(g * NSL + t) * 2 + 1] = cnt[t];
    }

    // pass 2: ordered scatter into the group's own CSR range (write-merging:
    // adjacent lanes with the same slice claim consecutive ranks)
    for (int i = t; i < staged; i += 1024) {
        const unsigned int w = stage[i];
        const unsigned int s = (w >> 16) & (NSL - 1);
        const unsigned int r = atomicAdd(&lcur[s], 1u);
        buck[(unsigned int)tokBase + off[s] + r] = w;
    }

    // overflow remainder (count > STAGE_CAP): statistically never; correctness.
    for (int i = staged + t; i < count; i += 1024) {
        const int gpos = tokBase + i;
        const int idx  = clip_idx(blocks[gpos] * bs + offsets[gpos], N);
        int lo = 0, hi = nh - 1;
        while (lo < hi) {
            int m = (lo + hi + 1) >> 1;
            if (lstart[m] <= gpos) lo = m; else hi = m - 1;
        }
        const int* row = entries + (long)idx * 5;
        int* o5 = out + (long)(h0 + lo) * 5;
        atomicXor(&o5[0], row[0]); atomicXor(&o5[1], row[1]);
        atomicXor(&o5[2], row[2]); atomicXor(&o5[3], row[3]);
        atomicXor(&o5[4], row[4]);
    }
}

// ---------------- Kernel B: XCD-pinned gather + LDS accumulate ----------------
// Grid = 2048 (resident capacity) so blockIdx&7 -> XCD round-robin holds.
// Block (x,g) touches only slices {x, x+8} -> 2.62 MB entries, L2-resident.
__global__ __launch_bounds__(256) void gather_kernel(
    const unsigned int* __restrict__ buck,
    const unsigned int* __restrict__ tab,
    const int* __restrict__ entries,
    int* __restrict__ out,
    int H, int NG, int nSl, int groupsPerBlock)
{
    __shared__ int acc[HPG * 5];

    const int B = blockIdx.x;
    const int x = B & 7;
    const int g0 = B >> 3;
    const int t = threadIdx.x;
    const int gStride = gridDim.x >> 3;

    for (int k = 0; k < groupsPerBlock; ++k) {
        const int g = g0 + k * gStride;
        if (g >= NG) break;

        for (int i = t; i < HPG * 5; i += 256) acc[i] = 0;
        __syncthreads();

        for (int s = x; s < nSl; s += 8) {
            const unsigned int base = tab[(g * NSL + s) * 2 + 0];
            const unsigned int cn   = tab[(g * NSL + s) * 2 + 1];
            for (unsigned int i = t; i < cn; i += 256) {
                const unsigned int w = buck[base + i];
                const int idx = (int)(w & 0xFFFFFu);
                const int h   = (int)(w >> 20);
                const int* row = entries + (long)idx * 5;
                atomicXor(&acc[h * 5 + 0], row[0]);
                atomicXor(&acc[h * 5 + 1], row[1]);
                atomicXor(&acc[h * 5 + 2], row[2]);
                atomicXor(&acc[h * 5 + 3], row[3]);
                atomicXor(&acc[h * 5 + 4], row[4]);
            }
        }
        __syncthreads();

        const long obase = (long)g * HPG * 5;
        const long omax  = (long)H * 5;
        for (int i = t; i < HPG * 5; i += 256) {
            const long o = obase + i;
            if (o < omax) {
                const int v = acc[i];
                if (v) atomicXor(&out[o], v);
            }
        }
        __syncthreads();
    }
}

// ---------------- Fallback (R1): direct gather, wave per hint ----------------
__global__ __launch_bounds__(256) void hint_xor_wave(
    const int* __restrict__ entries,
    const int* __restrict__ blocks,
    const int* __restrict__ offsets,
    const int* __restrict__ starts,
    const int* __restrict__ sizes,
    const int* __restrict__ bs_ptr,
    int* __restrict__ out,
    int H, int N)
{
    const int gtid = blockIdx.x * blockDim.x + threadIdx.x;
    const int hint = gtid >> 6;
    const int lane = gtid & 63;
    if (hint >= H) return;

    const int start = starts[hint];
    const int size  = sizes[hint];
    const int bs    = bs_ptr[0];

    int a0 = 0, a1 = 0, a2 = 0, a3 = 0, a4 = 0;
    for (int j = lane; j < size; j += 64) {
        int idx = clip_idx(blocks[start + j] * bs + offsets[start + j], N);
        const int* row = entries + (size_t)idx * 5;
        a0 ^= row[0]; a1 ^= row[1]; a2 ^= row[2]; a3 ^= row[3]; a4 ^= row[4];
    }
    #pragma unroll
    for (int m = 1; m < 64; m <<= 1) {
        a0 ^= __shfl_xor(a0, m);
        a1 ^= __shfl_xor(a1, m);
        a2 ^= __shfl_xor(a2, m);
        a3 ^= __shfl_xor(a3, m);
        a4 ^= __shfl_xor(a4, m);
    }
    if (lane == 0) {
        int* o = out + (size_t)hint * 5;
        o[0] = a0; o[1] = a1; o[2] = a2; o[3] = a3; o[4] = a4;
    }
}

extern "C" void kernel_launch(void* const* d_in, const int* in_sizes, int n_in,
                              void* d_out, int out_size, void* d_ws, size_t ws_size,
                              hipStream_t stream) {
    const int* entries = (const int*)d_in[0];
    const int* blocks  = (const int*)d_in[1];
    const int* offsets = (const int*)d_in[2];
    const int* starts  = (const int*)d_in[3];
    const int* sizes   = (const int*)d_in[4];
    const int* bs      = (const int*)d_in[5];
    int* out = (int*)d_out;

    const int H = in_sizes[3];
    const int T = in_sizes[1];
    const int N = in_sizes[0] / 5;

    const int NG  = (H + HPG - 1) / HPG;
    const int nSl = (N + 65535) >> 16;

    // ws layout: buck [T] u32 | tab [NG*NSL*2] u32
    const size_t buckOff  = 0;
    const size_t buckBytes = (size_t)T * 4;
    const size_t tabOff   = (buckOff + buckBytes + 63) & ~(size_t)63;
    const size_t need     = tabOff + (size_t)NG * NSL * 2 * 4 + 64;

    const bool ok = (N <= (1 << 20)) && (nSl <= NSL) && (ws_size >= need) &&
                    (H <= (1 << 27));   // hint fits u32 payload budget

    if (ok) {
        unsigned int* buck = (unsigned int*)((char*)d_ws + buckOff);
        unsigned int* tab  = (unsigned int*)((char*)d_ws + tabOff);

        hipMemsetAsync(d_out, 0, (size_t)out_size * sizeof(int), stream);

        hipLaunchKernelGGL(bucket_kernel, dim3(NG), dim3(1024), 0, stream,
                           blocks, offsets, starts, bs, entries, out,
                           buck, tab, H, N, T);

        int gridB = 2048;
        if (gridB > NG * 8) gridB = NG * 8;
        const int gStride = (gridB >= 8) ? (gridB >> 3) : 1;
        const int gpb = (NG + gStride - 1) / gStride;

        hipLaunchKernelGGL(gather_kernel, dim3(gridB), dim3(256), 0, stream,
                           buck, tab, entries, out, H, NG, nSl, gpb);
    } else {
        const long total_threads = (long)H * 64;
        const int block = 256;
        const int grid = (int)((total_threads + block - 1) / block);
        hipLaunchKernelGGL(hint_xor_wave, dim3(grid), dim3(block), 0, stream,
                           entries, blocks, offsets, starts, sizes, bs, out, H, N);
    }
}